// Round 2
// baseline (238.672 us; speedup 1.0000x reference)
//
#include <hip/hip_runtime.h>
#include <hip/hip_bf16.h>
#include <cstdint>
#include <cstddef>

#define T_TOK 2048
#define HDIM  1024
#define FDIM  2048
#define NEXP  8

#define BM 128
#define BN 64
#define BK 32
#define MT1 (T_TOK / BM)    // 16 m-tiles (worst case)
#define NT1 (FDIM / BN)     // 32 n-tiles (gate/up)
#define NT2 (HDIM / BN)     // 16 n-tiles (down)

typedef __attribute__((ext_vector_type(8))) short bf16x8;
typedef __attribute__((ext_vector_type(4))) float f32x4;

__device__ __forceinline__ unsigned short f2b(float f) {
  __hip_bfloat16 h = __float2bfloat16(f);
  return __builtin_bit_cast(unsigned short, h);
}

__device__ __forceinline__ void gload16(const void* g, void* l) {
  __builtin_amdgcn_global_load_lds(
      (const __attribute__((address_space(1))) unsigned int*)g,
      (__attribute__((address_space(3))) unsigned int*)l, 16, 0, 0);
}

// ---------------- fp32 -> bf16 weight conversion (grid-stride, 8 elems/iter) ----
__global__ __launch_bounds__(256) void conv_k(const float* __restrict__ s,
                                              unsigned short* __restrict__ d, int n8) {
  int i = blockIdx.x * blockDim.x + threadIdx.x;
  const int stride = gridDim.x * blockDim.x;
  for (; i < n8; i += stride) {
    const float4 f0 = ((const float4*)s)[2 * i];
    const float4 f1 = ((const float4*)s)[2 * i + 1];
    union { unsigned short u[8]; uint4 v; } p;
    p.u[0] = f2b(f0.x); p.u[1] = f2b(f0.y); p.u[2] = f2b(f0.z); p.u[3] = f2b(f0.w);
    p.u[4] = f2b(f1.x); p.u[5] = f2b(f1.y); p.u[6] = f2b(f1.z); p.u[7] = f2b(f1.w);
    ((uint4*)d)[i] = p.v;
  }
}

// ---------------- router + sparsemixer (eval) + x->bf16 ----------------
__global__ __launch_bounds__(256) void router_k(
    const float* __restrict__ x, const float* __restrict__ rw,
    float* __restrict__ wslot, int* __restrict__ rows,
    int* __restrict__ cnt, unsigned short* __restrict__ xb)
{
  const int wave = threadIdx.x >> 6, lane = threadIdx.x & 63;
  const int t = blockIdx.x * 4 + wave;
  const float* xr = x + (size_t)t * HDIM;
  unsigned short* xbr = xb + (size_t)t * HDIM;
  float acc[NEXP];
#pragma unroll
  for (int e = 0; e < NEXP; ++e) acc[e] = 0.f;
  for (int i = 0; i < HDIM / 64; ++i) {
    const int h = i * 64 + lane;
    const float xv = xr[h];
    xbr[h] = f2b(xv);
#pragma unroll
    for (int e = 0; e < NEXP; ++e) acc[e] += xv * rw[e * HDIM + h];
  }
#pragma unroll
  for (int e = 0; e < NEXP; ++e) {
#pragma unroll
    for (int off = 32; off; off >>= 1) acc[e] += __shfl_xor(acc[e], off);
  }
  if (lane == 0) {
    float m1 = acc[0]; int i1 = 0;
#pragma unroll
    for (int e = 1; e < NEXP; ++e) if (acc[e] > m1) { m1 = acc[e]; i1 = e; }
    float sum1 = 0.f;
#pragma unroll
    for (int e = 0; e < NEXP; ++e) {
      const float f = fmaxf(fabsf(acc[e]), m1);
      if (m1 - acc[e] <= 0.02f * f) sum1 += expf(acc[e] - m1);
    }
    float m2 = -3.4e38f; int i2 = 0;
#pragma unroll
    for (int e = 0; e < NEXP; ++e)
      if (e != i1 && acc[e] > m2) { m2 = acc[e]; i2 = e; }
    float sum2 = 0.f;
#pragma unroll
    for (int e = 0; e < NEXP; ++e) {
      if (e == i1) continue;
      const float f = fmaxf(fabsf(acc[e]), m2);
      if (m2 - acc[e] <= 0.02f * f) sum2 += expf(acc[e] - m2);
    }
    wslot[2 * t]     = 1.f / sum1;
    wslot[2 * t + 1] = 1.f / sum2;
    int p1 = atomicAdd(&cnt[i1], 1); rows[i1 * T_TOK + p1] = 2 * t;
    int p2 = atomicAdd(&cnt[i2], 1); rows[i2 * T_TOK + p2] = 2 * t + 1;
  }
}

// ---------------- gate/up GEMM: h = silu(x Wg^T) * (x Wu^T) * w ----------------
template <bool PRE>
__global__ __launch_bounds__(256) void gemm_gateup_k(
    const unsigned short* __restrict__ xb,
    const float* __restrict__ wg32, const float* __restrict__ wu32,
    const unsigned short* __restrict__ wg16, const unsigned short* __restrict__ wu16,
    const int* __restrict__ rows, const int* __restrict__ cnt,
    const float* __restrict__ wslot, unsigned short* __restrict__ hbuf)
{
  const int bx = blockIdx.x;
  const int e  = bx >> 9;          // / (MT1*NT1=512)
  const int rm = bx & 511;
  const int mt = rm >> 5;          // / NT1
  const int nt = rm & 31;
  const int cnt_e = cnt[e];
  if (mt * BM >= cnt_e) return;

  __shared__ unsigned short As[BM * BK];   // [128][32] linear
  __shared__ unsigned short Bg[BN * BK];   // [64][32]
  __shared__ unsigned short Bu[BN * BK];
  __shared__ int ldsRow[BM];

  const int tid = threadIdx.x;
  if (tid < BM) {
    const int idx = mt * BM + tid;
    ldsRow[tid] = (idx < cnt_e) ? rows[e * T_TOK + idx] : -1;
  }
  __syncthreads();

  const int lane = tid & 63, w = tid >> 6;
  const int wr = w >> 1, wc = w & 1;        // 2x2 wave grid; wave = 64(M) x 32(N) dual
  const int lr = lane & 15, lq = lane >> 4;

  // ---- staging geometry: each wave writes 16-row (1 KiB) blocks ----
  const int srow = lane >> 2;          // 0..15
  const int sk   = (lane & 3) * 8;     // bf16 chunk within a 32-elem row

  int ra0 = ldsRow[w * 16 + srow];      if (ra0 < 0) ra0 = 0;
  int ra1 = ldsRow[64 + w * 16 + srow]; if (ra1 < 0) ra1 = 0;
  const unsigned short* aS0 = xb + (size_t)(ra0 >> 1) * HDIM + sk;
  const unsigned short* aS1 = xb + (size_t)(ra1 >> 1) * HDIM + sk;
  unsigned short* aD0 = &As[(w * 16) * BK] + lane * 8;
  unsigned short* aD1 = &As[(64 + w * 16) * BK] + lane * 8;

  const int bn = nt * BN + w * 16 + srow;   // weight col for staging
  const unsigned short* bgS = wg16 + ((size_t)e * FDIM + bn) * HDIM + sk;
  const unsigned short* buS = wu16 + ((size_t)e * FDIM + bn) * HDIM + sk;
  unsigned short* bgD = &Bg[(w * 16) * BK] + lane * 8;
  unsigned short* buD = &Bu[(w * 16) * BK] + lane * 8;

  // fallback (fp32 weights, reg-convert) staging geometry
  const int frow = tid >> 2;           // 0..63
  const int fk   = (tid & 3) * 8;
  const float* fgS = wg32 + ((size_t)e * FDIM + nt * BN + frow) * HDIM + fk;
  const float* fuS = wu32 + ((size_t)e * FDIM + nt * BN + frow) * HDIM + fk;

  f32x4 accg[4][2], accu[4][2];
#pragma unroll
  for (int mf = 0; mf < 4; ++mf)
#pragma unroll
    for (int nf = 0; nf < 2; ++nf) {
      accg[mf][nf] = (f32x4){0.f, 0.f, 0.f, 0.f};
      accu[mf][nf] = (f32x4){0.f, 0.f, 0.f, 0.f};
    }

  for (int k0 = 0; k0 < HDIM; k0 += BK) {
    gload16(aS0 + k0, aD0);
    gload16(aS1 + k0, aD1);
    if (PRE) {
      gload16(bgS + k0, bgD);
      gload16(buS + k0, buD);
    } else {
      {
        const float4 f0 = *(const float4*)(fgS + k0);
        const float4 f1 = *(const float4*)(fgS + k0 + 4);
        union { unsigned short u[8]; uint4 v; } p;
        p.u[0] = f2b(f0.x); p.u[1] = f2b(f0.y); p.u[2] = f2b(f0.z); p.u[3] = f2b(f0.w);
        p.u[4] = f2b(f1.x); p.u[5] = f2b(f1.y); p.u[6] = f2b(f1.z); p.u[7] = f2b(f1.w);
        *(uint4*)(&Bg[frow * BK + fk]) = p.v;
      }
      {
        const float4 f0 = *(const float4*)(fuS + k0);
        const float4 f1 = *(const float4*)(fuS + k0 + 4);
        union { unsigned short u[8]; uint4 v; } p;
        p.u[0] = f2b(f0.x); p.u[1] = f2b(f0.y); p.u[2] = f2b(f0.z); p.u[3] = f2b(f0.w);
        p.u[4] = f2b(f1.x); p.u[5] = f2b(f1.y); p.u[6] = f2b(f1.z); p.u[7] = f2b(f1.w);
        *(uint4*)(&Bu[frow * BK + fk]) = p.v;
      }
    }
    __syncthreads();   // compiler drains vmcnt before barrier

    bf16x8 a[4], bg[2], bu[2];
#pragma unroll
    for (int mf = 0; mf < 4; ++mf)
      a[mf] = *(const bf16x8*)&As[(wr * 64 + mf * 16 + lr) * BK + lq * 8];
#pragma unroll
    for (int nf = 0; nf < 2; ++nf) {
      bg[nf] = *(const bf16x8*)&Bg[(wc * 32 + nf * 16 + lr) * BK + lq * 8];
      bu[nf] = *(const bf16x8*)&Bu[(wc * 32 + nf * 16 + lr) * BK + lq * 8];
    }
#pragma unroll
    for (int mf = 0; mf < 4; ++mf)
#pragma unroll
      for (int nf = 0; nf < 2; ++nf) {
        accg[mf][nf] = __builtin_amdgcn_mfma_f32_16x16x32_bf16(a[mf], bg[nf], accg[mf][nf], 0, 0, 0);
        accu[mf][nf] = __builtin_amdgcn_mfma_f32_16x16x32_bf16(a[mf], bu[nf], accu[mf][nf], 0, 0, 0);
      }
    __syncthreads();
  }

  // epilogue: h = silu(g)*u*w  (C/D frag: col=lane&15, row=(lane>>4)*4+i)
#pragma unroll
  for (int mf = 0; mf < 4; ++mf)
#pragma unroll
    for (int nf = 0; nf < 2; ++nf) {
      const int col = nt * BN + wc * 32 + nf * 16 + lr;
#pragma unroll
      for (int i = 0; i < 4; ++i) {
        const int lrow = wr * 64 + mf * 16 + lq * 4 + i;
        const int r = ldsRow[lrow];
        if (r < 0) continue;
        const float g = accg[mf][nf][i], u = accu[mf][nf][i];
        const float val = g / (1.f + __expf(-g)) * u * wslot[r];
        hbuf[(size_t)r * FDIM + col] = f2b(val);
      }
    }
}

// ---------------- down GEMM: out[t] += h Wd^T ----------------
template <bool PRE>
__global__ __launch_bounds__(256) void gemm_down_k(
    const unsigned short* __restrict__ hbuf,
    const float* __restrict__ wd32, const unsigned short* __restrict__ wd16,
    const int* __restrict__ rows, const int* __restrict__ cnt,
    float* __restrict__ out)
{
  const int bx = blockIdx.x;
  const int e  = bx >> 8;          // / (MT1*NT2=256)
  const int rm = bx & 255;
  const int mt = rm >> 4;          // / NT2
  const int nt = rm & 15;
  const int cnt_e = cnt[e];
  if (mt * BM >= cnt_e) return;

  __shared__ unsigned short As[BM * BK];
  __shared__ unsigned short Bs[BN * BK];
  __shared__ int ldsRow[BM];

  const int tid = threadIdx.x;
  if (tid < BM) {
    const int idx = mt * BM + tid;
    ldsRow[tid] = (idx < cnt_e) ? rows[e * T_TOK + idx] : -1;
  }
  __syncthreads();

  const int lane = tid & 63, w = tid >> 6;
  const int wr = w >> 1, wc = w & 1;
  const int lr = lane & 15, lq = lane >> 4;

  const int srow = lane >> 2;
  const int sk   = (lane & 3) * 8;

  int ra0 = ldsRow[w * 16 + srow];      if (ra0 < 0) ra0 = 0;
  int ra1 = ldsRow[64 + w * 16 + srow]; if (ra1 < 0) ra1 = 0;
  const unsigned short* aS0 = hbuf + (size_t)ra0 * FDIM + sk;
  const unsigned short* aS1 = hbuf + (size_t)ra1 * FDIM + sk;
  unsigned short* aD0 = &As[(w * 16) * BK] + lane * 8;
  unsigned short* aD1 = &As[(64 + w * 16) * BK] + lane * 8;

  const int bn = nt * BN + w * 16 + srow;
  const unsigned short* bS = wd16 + ((size_t)e * HDIM + bn) * FDIM + sk;
  unsigned short* bD = &Bs[(w * 16) * BK] + lane * 8;

  const int frow = tid >> 2;
  const int fk   = (tid & 3) * 8;
  const float* fS = wd32 + ((size_t)e * HDIM + nt * BN + frow) * FDIM + fk;

  f32x4 acc[4][2];
#pragma unroll
  for (int mf = 0; mf < 4; ++mf)
#pragma unroll
    for (int nf = 0; nf < 2; ++nf) acc[mf][nf] = (f32x4){0.f, 0.f, 0.f, 0.f};

  for (int k0 = 0; k0 < FDIM; k0 += BK) {
    gload16(aS0 + k0, aD0);
    gload16(aS1 + k0, aD1);
    if (PRE) {
      gload16(bS + k0, bD);
    } else {
      const float4 f0 = *(const float4*)(fS + k0);
      const float4 f1 = *(const float4*)(fS + k0 + 4);
      union { unsigned short u[8]; uint4 v; } p;
      p.u[0] = f2b(f0.x); p.u[1] = f2b(f0.y); p.u[2] = f2b(f0.z); p.u[3] = f2b(f0.w);
      p.u[4] = f2b(f1.x); p.u[5] = f2b(f1.y); p.u[6] = f2b(f1.z); p.u[7] = f2b(f1.w);
      *(uint4*)(&Bs[frow * BK + fk]) = p.v;
    }
    __syncthreads();

    bf16x8 a[4], b[2];
#pragma unroll
    for (int mf = 0; mf < 4; ++mf)
      a[mf] = *(const bf16x8*)&As[(wr * 64 + mf * 16 + lr) * BK + lq * 8];
#pragma unroll
    for (int nf = 0; nf < 2; ++nf)
      b[nf] = *(const bf16x8*)&Bs[(wc * 32 + nf * 16 + lr) * BK + lq * 8];
#pragma unroll
    for (int mf = 0; mf < 4; ++mf)
#pragma unroll
      for (int nf = 0; nf < 2; ++nf)
        acc[mf][nf] = __builtin_amdgcn_mfma_f32_16x16x32_bf16(a[mf], b[nf], acc[mf][nf], 0, 0, 0);
    __syncthreads();
  }

#pragma unroll
  for (int mf = 0; mf < 4; ++mf)
#pragma unroll
    for (int nf = 0; nf < 2; ++nf) {
      const int col = nt * BN + wc * 32 + nf * 16 + lr;
#pragma unroll
      for (int i = 0; i < 4; ++i) {
        const int lrow = wr * 64 + mf * 16 + lq * 4 + i;
        const int r = ldsRow[lrow];
        if (r < 0) continue;
        atomicAdd(&out[(size_t)(r >> 1) * HDIM + col], acc[mf][nf][i]);
      }
    }
}

extern "C" void kernel_launch(void* const* d_in, const int* in_sizes, int n_in,
                              void* d_out, int out_size, void* d_ws, size_t ws_size,
                              hipStream_t stream) {
  const float* x  = (const float*)d_in[0];   // [2,1024,1024]
  const float* rw = (const float*)d_in[1];   // [8,1024]
  const float* wg = (const float*)d_in[2];   // [8,2048,1024]
  const float* wu = (const float*)d_in[3];   // [8,2048,1024]
  const float* wd = (const float*)d_in[4];   // [8,1024,2048]
  float* out = (float*)d_out;

  char* ws = (char*)d_ws;
  unsigned short* hbuf = (unsigned short*)ws;                        // 16 MiB
  unsigned short* xb   = (unsigned short*)(ws + (16u << 20));        // 4 MiB
  int*   cnt   = (int*)  (ws + (20u << 20));                         // 256 B
  int*   rows  = (int*)  (ws + (20u << 20) + 256);                   // 64 KiB
  float* wslot = (float*)(ws + (20u << 20) + 256 + 65536);           // 16 KiB
  unsigned short* wg16 = (unsigned short*)(ws + (24ull << 20));      // 32 MiB
  unsigned short* wu16 = (unsigned short*)(ws + (56ull << 20));      // 32 MiB
  unsigned short* wd16 = (unsigned short*)(ws + (88ull << 20));      // 32 MiB
  const bool pre = ws_size >= (121ull << 20);

  hipMemsetAsync(cnt, 0, 256, stream);
  hipMemsetAsync(out, 0, (size_t)T_TOK * HDIM * sizeof(float), stream);
  router_k<<<T_TOK / 4, 256, 0, stream>>>(x, rw, wslot, rows, cnt, xb);

  const int nW = NEXP * FDIM * HDIM / 8;   // 2,097,152 uint4-groups per tensor
  if (pre) {
    conv_k<<<2048, 256, 0, stream>>>(wg, wg16, nW);
    conv_k<<<2048, 256, 0, stream>>>(wu, wu16, nW);
    conv_k<<<2048, 256, 0, stream>>>(wd, wd16, nW);
    gemm_gateup_k<true><<<NEXP * MT1 * NT1, 256, 0, stream>>>(xb, wg, wu, wg16, wu16,
                                                              rows, cnt, wslot, hbuf);
    gemm_down_k<true><<<NEXP * MT1 * NT2, 256, 0, stream>>>(hbuf, wd, wd16, rows, cnt, out);
  } else {
    gemm_gateup_k<false><<<NEXP * MT1 * NT1, 256, 0, stream>>>(xb, wg, wu, wg16, wu16,
                                                               rows, cnt, wslot, hbuf);
    gemm_down_k<false><<<NEXP * MT1 * NT2, 256, 0, stream>>>(hbuf, wd, wd16, rows, cnt, out);
  }
}